// Round 13
// baseline (83.319 us; speedup 1.0000x reference)
//
#include <hip/hip_runtime.h>

// Problem constants (from the reference):
//   B=32768 batch, T=256 trees, D=10 depth, F=512 features, C=1 leaf dim
constexpr int kB = 32768;
constexpr int kT = 256;
constexpr int kD = 10;
constexpr int kF = 512;
constexpr int kLvlPad = kT << (kD - 1); // 131072

constexpr int kRows    = 32;             // batch rows per block (32 lanes/tree)
constexpr int kTrees   = 128;            // trees per block (4 chains per thread)
constexpr int kChains  = 4;
constexpr int kThreads = 1024;           // 32 rows x 32 tree-slots
constexpr int kXPad    = 516;            // padded x row stride (floats)
constexpr int kOPad    = kTrees + 1;     // outs stride 129

// Workspace layout (int4 units):
//  P1[p]  : 512 recs  @ 0     — pair (levels 1,2), idx = level-1 global
//  P3[p]  : 2048 recs @ 512   — pair (levels 3,4), idx = level-3 global
//  P5[p]  : 8192 recs @ 2560  — pair (levels 5,6), idx = level-5 global
//  T789[p]: 32768 recs x 64B @ 10752 — levels 7,8,9 + 8 bf16 leaves, ONE
//           cache line per record. Biases exact f32 (decisions exact);
//           only leaf VALUES are bf16 (err <= ~0.009, threshold 0.09).
// Pair rec: {u32 n_top|nL<<9|nR<<18, f32 b_top, f32 bL, f32 bR}
// T789 rec (4 int4):
//  q0 = {n7|n8L<<16, n8R|n9LL<<16, n9LR|n9RL<<16, n9RR}
//  q1 = {b7, b8L, b8R, b9LL}
//  q2 = {b9LR, b9RL, b9RR, leaf01(bf16x2)}
//  q3 = {leaf23, leaf45, leaf67, pad}
constexpr int kO1 = 0;
constexpr int kO3 = 512;
constexpr int kO5 = 2560;
constexpr int kOT = 10752;               // 64B-aligned (10752*16 % 64 == 0)
constexpr int kNT = 32768;               // T789 record count
constexpr int kPrepThreads = kOT + kNT;  // 43520
constexpr size_t kWsBytes = (size_t)(kOT + 4 * kNT) * 16; // 2,269,184 B

__device__ __forceinline__ unsigned bf16_rne(float f) {
    unsigned u = __float_as_uint(f);
    return (u + 0x7fffu + ((u >> 16) & 1u)) >> 16;
}

// Build pair tables + T789 in one launch.
__global__ __launch_bounds__(256)
void prep_kernel(const int* __restrict__ nodes, const float* __restrict__ biases,
                 const float* __restrict__ leaf_nodes, int4* __restrict__ ws)
{
    int idx = blockIdx.x * 256 + threadIdx.x;
    if (idx < kOT) {
        int i, base;
        if      (idx < kO3) { i = 1; base = kO1; }
        else if (idx < kO5) { i = 3; base = kO3; }
        else                { i = 5; base = kO5; }
        int j = idx - base;                      // global index into level i
        const int*   nt = nodes  + (size_t)(i - 1) * kLvlPad; // level i
        const float* bt = biases + (size_t)(i - 1) * kLvlPad;
        const int*   nc = nodes  + (size_t)i * kLvlPad;       // level i+1
        const float* bc = biases + (size_t)i * kLvlPad;
        unsigned int pk = (unsigned int)nt[j]
                        | ((unsigned int)nc[2 * j]     << 9)
                        | ((unsigned int)nc[2 * j + 1] << 18);
        ws[idx] = make_int4((int)pk, __float_as_int(bt[j]),
                            __float_as_int(bc[2 * j]),
                            __float_as_int(bc[2 * j + 1]));
    } else if (idx < kPrepThreads) {
        int j = idx - kOT;                       // level-7 global index
        const int*   n7 = nodes  + (size_t)6 * kLvlPad;
        const float* b7 = biases + (size_t)6 * kLvlPad;
        const int*   n8 = nodes  + (size_t)7 * kLvlPad;
        const float* b8 = biases + (size_t)7 * kLvlPad;
        const int*   n9 = nodes  + (size_t)8 * kLvlPad;
        const float* b9 = biases + (size_t)8 * kLvlPad;
        unsigned a7  = (unsigned)n7[j];
        unsigned a8L = (unsigned)n8[2 * j],     a8R = (unsigned)n8[2 * j + 1];
        unsigned a9LL = (unsigned)n9[4 * j],     a9LR = (unsigned)n9[4 * j + 1];
        unsigned a9RL = (unsigned)n9[4 * j + 2], a9RR = (unsigned)n9[4 * j + 3];
        int4 q0 = make_int4((int)(a7  | (a8L  << 16)),
                            (int)(a8R | (a9LL << 16)),
                            (int)(a9LR | (a9RL << 16)),
                            (int)a9RR);
        int4 q1 = make_int4(__float_as_int(b7[j]),
                            __float_as_int(b8[2 * j]),
                            __float_as_int(b8[2 * j + 1]),
                            __float_as_int(b9[4 * j]));
        unsigned l0 = bf16_rne(leaf_nodes[8 * j])     | (bf16_rne(leaf_nodes[8 * j + 1]) << 16);
        unsigned l1 = bf16_rne(leaf_nodes[8 * j + 2]) | (bf16_rne(leaf_nodes[8 * j + 3]) << 16);
        unsigned l2 = bf16_rne(leaf_nodes[8 * j + 4]) | (bf16_rne(leaf_nodes[8 * j + 5]) << 16);
        unsigned l3 = bf16_rne(leaf_nodes[8 * j + 6]) | (bf16_rne(leaf_nodes[8 * j + 7]) << 16);
        int4 q2 = make_int4(__float_as_int(b9[4 * j + 1]),
                            __float_as_int(b9[4 * j + 2]),
                            __float_as_int(b9[4 * j + 3]),
                            (int)l0);
        int4 q3 = make_int4((int)l1, (int)l2, (int)l3, 0);
        int4* rp = ws + kOT + 4 * j;
        rp[0] = q0; rp[1] = q1; rp[2] = q2; rp[3] = q3;
    }
}

// R12 structure (32 rows x 128 trees, 1024 threads, 4 chains/thread,
// 32 lanes share each tree) with the tail restructured: chain is now
// root -> P1 -> P3 -> P5 -> T789 = 5 serial gathers. T789's 4 dwordx4
// loads hit ONE 64B line per record (1 fill + 3 hits), replacing the
// P7+FU two-line tail: lines/chain ~1.85 -> ~1.21, table set 2.17MB
// (fits per-XCD L2 with headroom). xs reused as output staging. Grid
// swizzled so the 2 tree-tiles of an x-tile sit 8 dispatch slots apart.
__global__ __launch_bounds__(kThreads)
void traverse_pair_kernel(const float* __restrict__ x,
                          const int* __restrict__ root_nodes,
                          const float* __restrict__ root_biases,
                          const int4* __restrict__ ws,
                          float* __restrict__ out)
{
    __shared__ float xs[kRows][kXPad];        // 66,048 B (reused for outs)
    float* outs = &xs[0][0];                  // alias: [kRows][kOPad]

    const int bid = blockIdx.x;
    const int w   = bid >> 4;        // 16-block window
    const int s   = bid & 15;
    const int bx  = w * 8 + (s & 7); // x-tile, [0, 1024)
    const int by  = s >> 3;          // tree tile, [0, 2)
    const int b0  = bx * kRows;
    const int t0  = by * kTrees;
    const int tid = threadIdx.x;

    // Stage 32 x rows (4096 float4), coalesced.
    {
        const float4* xg = reinterpret_cast<const float4*>(x + (size_t)b0 * kF);
#pragma unroll
        for (int k = 0; k < 4; ++k) {
            int j = tid + k * kThreads;   // 0..4095
            int r = j >> 7;
            int c = j & 127;
            float4 v = xg[(size_t)r * (kF / 4) + c];
            *reinterpret_cast<float4*>(&xs[r][c * 4]) = v;
        }
    }
    __syncthreads();

    const int r  = tid & (kRows - 1); // row within tile (= lane&31)
    const int tt = tid >> 5;          // 0..31 (tree slot)
    const float* __restrict__ xrow = xs[r];

    int p[kChains];
#pragma unroll
    for (int c = 0; c < kChains; ++c) {
        int t = t0 + tt + 32 * c;
        p[c] = 2 * t + (xrow[root_nodes[t]] <= root_biases[t] ? 1 : 0);
    }

    const int4* __restrict__ P1 = ws + kO1;
    const int4* __restrict__ P3 = ws + kO3;
    const int4* __restrict__ P5 = ws + kO5;
    const int4* __restrict__ T9 = ws + kOT;

    // Pair step: one 16B gather advances two levels.
#define PAIR_STEP(TBL)                                                        \
    {                                                                         \
        int4 rec[kChains];                                                    \
        _Pragma("unroll")                                                     \
        for (int c = 0; c < kChains; ++c) rec[c] = TBL[p[c]];                 \
        _Pragma("unroll")                                                     \
        for (int c = 0; c < kChains; ++c) {                                   \
            unsigned int n = (unsigned int)rec[c].x;                          \
            int c0 = xrow[n & 511u] <= __int_as_float(rec[c].y) ? 1 : 0;      \
            int nc = c0 ? (int)((n >> 18) & 511u) : (int)((n >> 9) & 511u);   \
            int bb = c0 ? rec[c].w : rec[c].z;                                \
            int c1 = xrow[nc] <= __int_as_float(bb) ? 1 : 0;                  \
            p[c] = 4 * p[c] + 2 * c0 + c1;                                    \
        }                                                                     \
    }

    PAIR_STEP(P1)   // levels 1,2  -> p in [0, 2048)
    PAIR_STEP(P3)   // levels 3,4  -> p in [0, 8192)
    PAIR_STEP(P5)   // levels 5,6  -> p in [0, 32768)
#undef PAIR_STEP

    // Triple-fused tail: levels 7,8,9 + bf16 leaf, one 64B line per chain.
    float leaf[kChains];
    {
        int4 q0[kChains], q1[kChains], q2[kChains], q3[kChains];
#pragma unroll
        for (int c = 0; c < kChains; ++c) {
            const int4* rp = T9 + 4 * p[c];
            q0[c] = rp[0]; q1[c] = rp[1]; q2[c] = rp[2]; q3[c] = rp[3];
        }
#pragma unroll
        for (int c = 0; c < kChains; ++c) {
            unsigned w0 = (unsigned)q0[c].x, w1 = (unsigned)q0[c].y;
            unsigned w2 = (unsigned)q0[c].z, w3 = (unsigned)q0[c].w;
            int c7 = xrow[w0 & 0xffffu] <= __int_as_float(q1[c].x) ? 1 : 0;
            unsigned n8 = c7 ? (w1 & 0xffffu) : (w0 >> 16);
            float    b8 = __int_as_float(c7 ? q1[c].z : q1[c].y);
            int c8 = xrow[n8] <= b8 ? 1 : 0;
            unsigned n9 = c7 ? (c8 ? (w3 & 0xffffu) : (w2 >> 16))
                             : (c8 ? (w2 & 0xffffu) : (w1 >> 16));
            float    b9 = __int_as_float(c7 ? (c8 ? q2[c].z : q2[c].y)
                                            : (c8 ? q2[c].x : q1[c].w));
            int c9 = xrow[n9] <= b9 ? 1 : 0;
            unsigned lp = (unsigned)(c7 ? (c8 ? q3[c].z : q3[c].y)
                                        : (c8 ? q3[c].x : q2[c].w));
            unsigned lb = c9 ? (lp >> 16) : (lp & 0xffffu);
            leaf[c] = __int_as_float((int)(lb << 16));
        }
    }

    // xs is dead now; reuse it as the output staging buffer.
    __syncthreads();
#pragma unroll
    for (int c = 0; c < kChains; ++c)
        outs[r * kOPad + tt + 32 * c] = leaf[c];
    __syncthreads();

#pragma unroll
    for (int k = 0; k < 4; ++k) {
        int j    = tid + k * kThreads;  // 0..4095
        int orow = j >> 7;              // 0..31
        int ocol = j & 127;             // 0..127
        __builtin_nontemporal_store(outs[orow * kOPad + ocol],
                                    &out[(size_t)(b0 + orow) * kT + t0 + ocol]);
    }
}

// Fallback (no workspace): straightforward per-level walk.
__global__ __launch_bounds__(512)
void traverse_plain_kernel(const float* __restrict__ x,
                           const int* __restrict__ root_nodes,
                           const float* __restrict__ root_biases,
                           const int* __restrict__ nodes,
                           const float* __restrict__ biases,
                           const float* __restrict__ leaf_nodes,
                           float* __restrict__ out)
{
    __shared__ float xs[16][kXPad];
    __shared__ float outs[16][65];

    const int b0  = blockIdx.x * 16;
    const int t0  = blockIdx.y * 64;
    const int tid = threadIdx.x;

    {
        const float4* xg = reinterpret_cast<const float4*>(x + (size_t)b0 * kF);
#pragma unroll
        for (int k = 0; k < 4; ++k) {
            int j = tid + k * 512;
            int r = j >> 7;
            int c = j & 127;
            float4 v = xg[(size_t)r * (kF / 4) + c];
            *reinterpret_cast<float4*>(&xs[r][c * 4]) = v;
        }
    }
    __syncthreads();

    const int r  = tid & 15;
    const int tt = tid >> 4;
    const int tA = t0 + tt;
    const int tB = t0 + tt + 32;
    const float* __restrict__ xrow = xs[r];

    int pA = 2 * tA + (xrow[root_nodes[tA]] <= root_biases[tA] ? 1 : 0);
    int pB = 2 * tB + (xrow[root_nodes[tB]] <= root_biases[tB] ? 1 : 0);

#pragma unroll
    for (int i = 1; i < kD; ++i) {
        const int*   ln = nodes  + (size_t)(i - 1) * kLvlPad;
        const float* lb = biases + (size_t)(i - 1) * kLvlPad;
        int   nA = ln[pA], nB = ln[pB];
        float bA = lb[pA], bB = lb[pB];
        pA = 2 * pA + (xrow[nA] <= bA ? 1 : 0);
        pB = 2 * pB + (xrow[nB] <= bB ? 1 : 0);
    }

    outs[r][tt]      = leaf_nodes[pA];
    outs[r][tt + 32] = leaf_nodes[pB];
    __syncthreads();

#pragma unroll
    for (int k = 0; k < 2; ++k) {
        int j    = tid + k * 512;
        int orow = j >> 6;
        int ocol = j & 63;
        __builtin_nontemporal_store(outs[orow][ocol],
                                    &out[(size_t)(b0 + orow) * kT + t0 + ocol]);
    }
}

extern "C" void kernel_launch(void* const* d_in, const int* in_sizes, int n_in,
                              void* d_out, int out_size, void* d_ws, size_t ws_size,
                              hipStream_t stream) {
    const float* x           = (const float*)d_in[0];
    const int*   root_nodes  = (const int*)d_in[1];
    const float* root_biases = (const float*)d_in[2];
    const int*   nodes       = (const int*)d_in[3];
    const float* biases      = (const float*)d_in[4];
    const float* leaf_nodes  = (const float*)d_in[5];
    float*       out         = (float*)d_out;

    if (ws_size >= kWsBytes) {
        prep_kernel<<<(kPrepThreads + 255) / 256, 256, 0, stream>>>(
            nodes, biases, leaf_nodes, (int4*)d_ws);
        const int nblocks = (kB / kRows) * (kT / kTrees); // 1024 * 2 = 2048
        traverse_pair_kernel<<<nblocks, kThreads, 0, stream>>>(
            x, root_nodes, root_biases, (const int4*)d_ws, out);
    } else {
        dim3 grid(kB / 16, kT / 64); // (2048, 4)
        traverse_plain_kernel<<<grid, 512, 0, stream>>>(
            x, root_nodes, root_biases, nodes, biases, leaf_nodes, out);
    }
}

// Round 14
// 58.025 us; speedup vs baseline: 1.4359x; 1.4359x over previous
//
#include <hip/hip_runtime.h>

// Problem constants (from the reference):
//   B=32768 batch, T=256 trees, D=10 depth, F=512 features, C=1 leaf dim
constexpr int kB = 32768;
constexpr int kT = 256;
constexpr int kD = 10;
constexpr int kF = 512;
constexpr int kLvlPad = kT << (kD - 1); // 131072
constexpr int kLevels = kD - 1;         // 9

constexpr int kRows    = 32;             // batch rows per block (32 lanes/tree)
constexpr int kTrees   = 256;            // trees per block = ALL trees
constexpr int kChains  = 8;              // chains per thread
constexpr int kThreads = 1024;           // 32 rows x 32 tree-slots
constexpr int kXPad    = 516;            // padded x row stride (floats)
constexpr int kOPad    = kTrees + 1;     // outs stride 257 -> conflict-free

// Pair-table record counts / offsets (16B records in d_ws) — R12 layout.
// Pair (i,i+1) table indexed by the GLOBAL level-i index (width T*2^i):
//   {u32 n_top|nL<<9|nR<<18, f32 b_top, f32 bL, f32 bR}  (node idx < 512)
// One dwordx4 gather advances TWO levels. Fused record (level 9 + leaf):
//   {n9, b9, leaf[2j], leaf[2j+1]} indexed by global level-9 index.
constexpr int kP1 = kT * 2;      // 512
constexpr int kP3 = kT * 8;      // 2048
constexpr int kP5 = kT * 32;     // 8192
constexpr int kP7 = kT * 128;    // 32768
constexpr int kFU = kT * 512;    // 131072
constexpr int kO1 = 0;
constexpr int kO3 = kO1 + kP1;   // 512
constexpr int kO5 = kO3 + kP3;   // 2560
constexpr int kO7 = kO5 + kP5;   // 10752
constexpr int kOF = kO7 + kP7;   // 43520
constexpr int kTotalRecs = kOF + kFU; // 174592
constexpr size_t kWsBytes = (size_t)kTotalRecs * 16; // 2,793,472 B

// Build all pair tables + fused table in one launch.
__global__ __launch_bounds__(256)
void prep_kernel(const int* __restrict__ nodes, const float* __restrict__ biases,
                 const float* __restrict__ leaf_nodes, int4* __restrict__ ws)
{
    int idx = blockIdx.x * 256 + threadIdx.x;
    if (idx < kOF) {
        int i, base;
        if      (idx < kO3) { i = 1; base = kO1; }
        else if (idx < kO5) { i = 3; base = kO3; }
        else if (idx < kO7) { i = 5; base = kO5; }
        else                { i = 7; base = kO7; }
        int j = idx - base;                      // global index into level i
        const int*   nt = nodes  + (size_t)(i - 1) * kLvlPad; // level i
        const float* bt = biases + (size_t)(i - 1) * kLvlPad;
        const int*   nc = nodes  + (size_t)i * kLvlPad;       // level i+1
        const float* bc = biases + (size_t)i * kLvlPad;
        unsigned int pk = (unsigned int)nt[j]
                        | ((unsigned int)nc[2 * j]     << 9)
                        | ((unsigned int)nc[2 * j + 1] << 18);
        ws[idx] = make_int4((int)pk, __float_as_int(bt[j]),
                            __float_as_int(bc[2 * j]),
                            __float_as_int(bc[2 * j + 1]));
    } else if (idx < kTotalRecs) {
        int j = idx - kOF;                       // global index into level 9
        const int   n9 = nodes [(size_t)(kD - 2) * kLvlPad + j];
        const float b9 = biases[(size_t)(kD - 2) * kLvlPad + j];
        ws[idx] = make_int4(n9, __float_as_int(b9),
                            __float_as_int(leaf_nodes[2 * j]),
                            __float_as_int(leaf_nodes[2 * j + 1]));
    }
}

// R12 structure with ONE change: 8 chains per thread (kTrees=256 — each
// block walks ALL trees for its 32 batch rows). Lookups/chain unchanged;
// per-thread MLP doubles (8 deep gathers in flight), waves halve, and each
// x-tile is read by exactly one block (no tree-tile split, no swizzle
// needed). Block = 32 rows x 32 tree-slots = 1024 threads; 32 lanes share
// each tree so pair gathers coalesce in the tree's window. Chain: root ->
// P1 -> P3 -> P5 -> P7 -> FU = 6 dependent gathers. xs (66KB) reused as
// output staging -> 2 blocks/CU.
__global__ __launch_bounds__(kThreads)
void traverse_pair_kernel(const float* __restrict__ x,
                          const int* __restrict__ root_nodes,
                          const float* __restrict__ root_biases,
                          const int4* __restrict__ ws,
                          float* __restrict__ out)
{
    __shared__ float xs[kRows][kXPad];        // 66,048 B (reused for outs)
    float* outs = &xs[0][0];                  // alias: [kRows][kOPad]

    const int b0  = blockIdx.x * kRows;
    const int tid = threadIdx.x;

    // Stage 32 x rows (4096 float4), coalesced.
    {
        const float4* xg = reinterpret_cast<const float4*>(x + (size_t)b0 * kF);
#pragma unroll
        for (int k = 0; k < 4; ++k) {
            int j = tid + k * kThreads;   // 0..4095
            int r = j >> 7;
            int c = j & 127;
            float4 v = xg[(size_t)r * (kF / 4) + c];
            *reinterpret_cast<float4*>(&xs[r][c * 4]) = v;
        }
    }
    __syncthreads();

    const int r  = tid & (kRows - 1); // row within tile (= lane&31)
    const int tt = tid >> 5;          // 0..31 (tree slot)
    const float* __restrict__ xrow = xs[r];

    int p[kChains];
#pragma unroll
    for (int c = 0; c < kChains; ++c) {
        int t = tt + 32 * c;          // 8 chains cover all 256 trees
        p[c] = 2 * t + (xrow[root_nodes[t]] <= root_biases[t] ? 1 : 0);
    }

    const int4* __restrict__ P1 = ws + kO1;
    const int4* __restrict__ P3 = ws + kO3;
    const int4* __restrict__ P5 = ws + kO5;
    const int4* __restrict__ P7 = ws + kO7;
    const int4* __restrict__ FU = ws + kOF;

    // Pair step: one 16B gather advances two levels (proven R12 form).
#define PAIR_STEP(TBL)                                                        \
    {                                                                         \
        int4 rec[kChains];                                                    \
        _Pragma("unroll")                                                     \
        for (int c = 0; c < kChains; ++c) rec[c] = TBL[p[c]];                 \
        _Pragma("unroll")                                                     \
        for (int c = 0; c < kChains; ++c) {                                   \
            unsigned int n = (unsigned int)rec[c].x;                          \
            int c0 = xrow[n & 511u] <= __int_as_float(rec[c].y) ? 1 : 0;      \
            int nc = c0 ? (int)((n >> 18) & 511u) : (int)((n >> 9) & 511u);   \
            int bb = c0 ? rec[c].w : rec[c].z;                                \
            int c1 = xrow[nc] <= __int_as_float(bb) ? 1 : 0;                  \
            p[c] = 4 * p[c] + 2 * c0 + c1;                                    \
        }                                                                     \
    }

    PAIR_STEP(P1)   // levels 1,2
    PAIR_STEP(P3)   // levels 3,4
    PAIR_STEP(P5)   // levels 5,6
    PAIR_STEP(P7)   // levels 7,8
#undef PAIR_STEP

    // Fused level 9 + leaf: one 16B gather finishes each tree.
    float leaf[kChains];
    {
        int4 rec[kChains];
#pragma unroll
        for (int c = 0; c < kChains; ++c) rec[c] = FU[p[c]];
#pragma unroll
        for (int c = 0; c < kChains; ++c) {
            leaf[c] = __int_as_float(
                xrow[rec[c].x] <= __int_as_float(rec[c].y) ? rec[c].w
                                                           : rec[c].z);
        }
    }

    // xs is dead now; reuse it as the output staging buffer.
    __syncthreads();
#pragma unroll
    for (int c = 0; c < kChains; ++c)
        outs[r * kOPad + tt + 32 * c] = leaf[c];
    __syncthreads();

#pragma unroll
    for (int k = 0; k < 8; ++k) {
        int j    = tid + k * kThreads;  // 0..8191
        int orow = j >> 8;              // 0..31
        int ocol = j & 255;             // 0..255
        __builtin_nontemporal_store(outs[orow * kOPad + ocol],
                                    &out[(size_t)(b0 + orow) * kT + ocol]);
    }
}

// Fallback (no workspace): straightforward per-level walk.
__global__ __launch_bounds__(512)
void traverse_plain_kernel(const float* __restrict__ x,
                           const int* __restrict__ root_nodes,
                           const float* __restrict__ root_biases,
                           const int* __restrict__ nodes,
                           const float* __restrict__ biases,
                           const float* __restrict__ leaf_nodes,
                           float* __restrict__ out)
{
    __shared__ float xs[16][kXPad];
    __shared__ float outs[16][65];

    const int b0  = blockIdx.x * 16;
    const int t0  = blockIdx.y * 64;
    const int tid = threadIdx.x;

    {
        const float4* xg = reinterpret_cast<const float4*>(x + (size_t)b0 * kF);
#pragma unroll
        for (int k = 0; k < 4; ++k) {
            int j = tid + k * 512;
            int r = j >> 7;
            int c = j & 127;
            float4 v = xg[(size_t)r * (kF / 4) + c];
            *reinterpret_cast<float4*>(&xs[r][c * 4]) = v;
        }
    }
    __syncthreads();

    const int r  = tid & 15;
    const int tt = tid >> 4;
    const int tA = t0 + tt;
    const int tB = t0 + tt + 32;
    const float* __restrict__ xrow = xs[r];

    int pA = 2 * tA + (xrow[root_nodes[tA]] <= root_biases[tA] ? 1 : 0);
    int pB = 2 * tB + (xrow[root_nodes[tB]] <= root_biases[tB] ? 1 : 0);

#pragma unroll
    for (int i = 1; i < kD; ++i) {
        const int*   ln = nodes  + (size_t)(i - 1) * kLvlPad;
        const float* lb = biases + (size_t)(i - 1) * kLvlPad;
        int   nA = ln[pA], nB = ln[pB];
        float bA = lb[pA], bB = lb[pB];
        pA = 2 * pA + (xrow[nA] <= bA ? 1 : 0);
        pB = 2 * pB + (xrow[nB] <= bB ? 1 : 0);
    }

    outs[r][tt]      = leaf_nodes[pA];
    outs[r][tt + 32] = leaf_nodes[pB];
    __syncthreads();

#pragma unroll
    for (int k = 0; k < 2; ++k) {
        int j    = tid + k * 512;
        int orow = j >> 6;
        int ocol = j & 63;
        __builtin_nontemporal_store(outs[orow][ocol],
                                    &out[(size_t)(b0 + orow) * kT + t0 + ocol]);
    }
}

extern "C" void kernel_launch(void* const* d_in, const int* in_sizes, int n_in,
                              void* d_out, int out_size, void* d_ws, size_t ws_size,
                              hipStream_t stream) {
    const float* x           = (const float*)d_in[0];
    const int*   root_nodes  = (const int*)d_in[1];
    const float* root_biases = (const float*)d_in[2];
    const int*   nodes       = (const int*)d_in[3];
    const float* biases      = (const float*)d_in[4];
    const float* leaf_nodes  = (const float*)d_in[5];
    float*       out         = (float*)d_out;

    if (ws_size >= kWsBytes) {
        prep_kernel<<<(kTotalRecs + 255) / 256, 256, 0, stream>>>(
            nodes, biases, leaf_nodes, (int4*)d_ws);
        const int nblocks = kB / kRows; // 1024
        traverse_pair_kernel<<<nblocks, kThreads, 0, stream>>>(
            x, root_nodes, root_biases, (const int4*)d_ws, out);
    } else {
        dim3 grid(kB / 16, kT / 64); // (2048, 4)
        traverse_plain_kernel<<<grid, 512, 0, stream>>>(
            x, root_nodes, root_biases, nodes, biases, leaf_nodes, out);
    }
}